// Round 14
// baseline (29.271 us; speedup 1.0000x reference)
//
#include <hip/hip_runtime.h>
#include <math.h>

#define DD 1024   // total dim
#define NN 128    // nodes
#define BB 8      // batch
#define KNBR 8    // neighbors
#define NH 8      // heads
#define LL 128    // latent

typedef __attribute__((ext_vector_type(8))) short short8v;
typedef __attribute__((ext_vector_type(4))) float f32x4;
typedef __attribute__((ext_vector_type(16))) float f32x16;

#define GLDS(gptr, lptr)                                                      \
  __builtin_amdgcn_global_load_lds(                                           \
      (const __attribute__((address_space(1))) void*)(gptr),                  \
      (__attribute__((address_space(3))) void*)(lptr), 16, 0, 0)

__device__ __forceinline__ unsigned short f2bf(float x) {
  unsigned u = __float_as_uint(x);
  unsigned r = u + 0x7fff + ((u >> 16) & 1);   // round-to-nearest-even
  return (unsigned short)(r >> 16);
}
__device__ __forceinline__ float bf2f(unsigned short u) {
  return __uint_as_float((unsigned)u << 16);
}

// ---------------------------------------------------------------------------
// Prep: z<3 -> convert+transpose W[z] (64x64 LDS tiles); z==3 -> convert E.
// grid (16,16,4), 256 threads.   [proven since R2]
// ---------------------------------------------------------------------------
__global__ __launch_bounds__(256)
void prep(const float* __restrict__ E,
          const float* __restrict__ Wl, const float* __restrict__ Wa,
          const float* __restrict__ Wh,
          unsigned short* __restrict__ Eb, unsigned short* __restrict__ Wt) {
  const int z = blockIdx.z;
  const int t = threadIdx.x;

  if (z == 3) {   // E convert: 256 blocks x 256 threads x 16 elems
    const int bid = blockIdx.y * 16 + blockIdx.x;
    const int i0 = bid * 4096 + t * 16;
    #pragma unroll
    for (int q = 0; q < 2; ++q) {
      const int i = i0 + q * 8;
      float4 a = *(const float4*)&E[i];
      float4 c = *(const float4*)&E[i + 4];
      union { unsigned short u[8]; uint4 v; } o;
      o.u[0] = f2bf(a.x); o.u[1] = f2bf(a.y); o.u[2] = f2bf(a.z); o.u[3] = f2bf(a.w);
      o.u[4] = f2bf(c.x); o.u[5] = f2bf(c.y); o.u[6] = f2bf(c.z); o.u[7] = f2bf(c.w);
      *(uint4*)&Eb[i] = o.v;
    }
    return;
  }

  const float* W = (z == 0) ? Wl : (z == 1) ? Wa : Wh;
  unsigned short* out = Wt + (size_t)z * DD * DD;

  __shared__ unsigned short tile[64][65];
  const int tx = t & 15, ty = t >> 4;
  const int r0 = blockIdx.y * 64, c0 = blockIdx.x * 64;

  #pragma unroll
  for (int i = 0; i < 4; ++i) {
    const int r = ty + i * 16;
    float4 v = *(const float4*)&W[(size_t)(r0 + r) * DD + c0 + tx * 4];
    tile[r][tx * 4 + 0] = f2bf(v.x);
    tile[r][tx * 4 + 1] = f2bf(v.y);
    tile[r][tx * 4 + 2] = f2bf(v.z);
    tile[r][tx * 4 + 3] = f2bf(v.w);
  }
  __syncthreads();
  #pragma unroll
  for (int i = 0; i < 4; ++i) {
    const int rr = ty + i * 16;   // output row = W column c0+rr
    ushort4 o;
    o.x = tile[tx * 4 + 0][rr];
    o.y = tile[tx * 4 + 1][rr];
    o.z = tile[tx * 4 + 2][rr];
    o.w = tile[tx * 4 + 3][rr];
    *(ushort4*)&out[(size_t)(c0 + rr) * DD + r0 + tx * 4] = o;
  }
}

// ---------------------------------------------------------------------------
// MFMA GEMM + hidden adj scan. Grid 1024, bijective XCD swizzle:
// per-XCD locals 0..95 = GEMM jobs (768, 3 blocks/CU), 96..127 = adj-scan
// jobs (256, dispatched last -> hide under gemm).
// GEMM: 64x64 tile, BK=64, 256 thr = 4 waves, wave tile 32x32 via ONE
// v_mfma_f32_32x32x16_bf16 per K-16 (4 MFMA + 8 ds_read_b128 per step,
// -17% MFMA cycles vs 8x 16x16x32). 3-buffer LDS, counted vmcnt(4) +
// raw s_barrier, XOR-swizzle, setprio around MFMA cluster.
// ---------------------------------------------------------------------------
__global__ __launch_bounds__(256)
void gemm3_mfma(const unsigned short* __restrict__ Eb,
                const unsigned short* __restrict__ Wt,
                const float* __restrict__ bl, const float* __restrict__ ba,
                const float* __restrict__ bh,
                const float* __restrict__ adj, int* __restrict__ idxbuf,
                unsigned short* __restrict__ Ylb,
                unsigned short* __restrict__ Yab,
                unsigned short* __restrict__ Yhb) {
  const int orig = blockIdx.x;
  const int xcd = orig & 7;
  const int local = orig >> 3;       // 0..127 per XCD

  const int t = threadIdx.x;

  if (local >= 96) {   // ---- adj one-hot scan: 4 nodes/block, 1 wave/node ----
    const int s = xcd * 32 + (local - 96);   // 0..255
    const int bi = s * 4 + (t >> 6);         // 0..1023
    const int lane = t & 63;
    const int k = lane >> 3;                 // neighbor row 0..7
    const int c0 = (lane & 7) * 16;          // this lane scans 16 cols
    const int rbase = (bi >> 7) * NN;
    const float* row = adj + ((size_t)bi * KNBR + k) * NN + c0;
    int found = -1;
    #pragma unroll
    for (int q = 0; q < 4; ++q) {
      float4 v = *(const float4*)&row[q * 4];
      const int base = c0 + q * 4;
      if (v.x > 0.5f) found = base;
      if (v.y > 0.5f) found = base + 1;
      if (v.z > 0.5f) found = base + 2;
      if (v.w > 0.5f) found = base + 3;
    }
    if (found >= 0) idxbuf[bi * KNBR + k] = rbase + found;
    return;
  }

  const int job = xcd * 96 + local;  // 0..767
  const int mat = job >> 8;          // /256
  const int rem = job & 255;
  const int bx = rem >> 4;           // col panel 0..15
  const int by = rem & 15;           // row panel 0..15

  const unsigned short* Bg = Wt + (size_t)mat * DD * DD;
  const float* bias = (mat == 0) ? bl : (mat == 1) ? ba : bh;

  __shared__ unsigned short As[3][64 * 64];
  __shared__ unsigned short Bs[3][64 * 64];

  const int lane = t & 63;
  const int w = t >> 6;            // wave 0..3
  const int wr = w >> 1, wc = w & 1;
  const int brow = by * 64, bcol = bx * 64;

  // staging: thread t -> tile row (t>>3) [+32 for 2nd issue], chunk (t&7).
  // swizzle: LDS row r, linear chunk q holds global chunk q ^ (r&7).
  const int srow = t >> 3;                      // 0..31
  const int sk = (((t & 7) ^ (srow & 7)) * 8);  // source k-offset (elems)
  const unsigned short* gA = Eb + (size_t)(brow + srow) * DD + sk;
  const unsigned short* gB = Bg + (size_t)(bcol + srow) * DD + sk;
  const int ldsoff = w * 512;   // elems; wave-uniform base (+ lane*16B by HW)

  // 32x32x16 fragment indices: A row = wr*32+(lane&31), k-grp = lane>>5;
  // chunk (8 elems) for kk = kk*2 + (lane>>5), XOR'd with row&7.
  const int lr32 = lane & 31, kg = lane >> 5;
  int aidx[4], bidx[4];
  #pragma unroll
  for (int kk = 0; kk < 4; ++kk) {
    const int ca = kk * 2 + kg;
    const int ra = wr * 32 + lr32;
    aidx[kk] = ra * 64 + ((ca ^ (ra & 7)) * 8);
    const int rb = wc * 32 + lr32;
    bidx[kk] = rb * 64 + ((ca ^ (rb & 7)) * 8);
  }

  // preload bias (one col per lane) and force completion (vmcnt ledger exact)
  float bvv = bias[bcol + wc * 32 + lr32];
  asm volatile("" : "+v"(bvv));

  f32x16 acc = {};

#define STAGE(q, kt) do {                                                     \
    const int k0_ = (kt) * 64;                                                \
    GLDS(gA + k0_,           &As[q][ldsoff]);                                 \
    GLDS(gA + k0_ + 32 * DD, &As[q][2048 + ldsoff]);                          \
    GLDS(gB + k0_,           &Bs[q][ldsoff]);                                 \
    GLDS(gB + k0_ + 32 * DD, &Bs[q][2048 + ldsoff]);                          \
  } while (0)

  STAGE(0, 0);   // 4 vm ops in flight
  STAGE(1, 1);   // 8 in flight

  #pragma unroll
  for (int kt = 0; kt < 16; ++kt) {
    const int p = kt % 3;
    // wait for tile kt's 4 loads (oldest); tile kt+1's 4 stay in flight
    if (kt != 15) asm volatile("s_waitcnt vmcnt(4)" ::: "memory");
    else          asm volatile("s_waitcnt vmcnt(0)" ::: "memory");
    __builtin_amdgcn_s_barrier();   // buf p landed; reads of buf (p+2)%3 done
    if (kt + 2 < 16) STAGE((kt + 2) % 3, kt + 2);   // overwrite tile kt-1's buf

    short8v a[4], b[4];
    #pragma unroll
    for (int kk = 0; kk < 4; ++kk) {
      a[kk] = *(const short8v*)&As[p][aidx[kk]];
      b[kk] = *(const short8v*)&Bs[p][bidx[kk]];
    }

    __builtin_amdgcn_s_setprio(1);
    #pragma unroll
    for (int kk = 0; kk < 4; ++kk)
      acc = __builtin_amdgcn_mfma_f32_32x32x16_bf16(a[kk], b[kk], acc, 0, 0, 0);
    __builtin_amdgcn_s_setprio(0);
  }
#undef STAGE

  // C-write: bias + relu, bf16.
  // 32x32 C/D layout: col = lane&31, row = (reg&3) + 8*(reg>>2) + 4*(lane>>5)
  unsigned short* Yo = (mat == 0) ? Ylb : (mat == 1) ? Yab : Yhb;
  const int col = bcol + wc * 32 + lr32;
  const int rb0 = brow + wr * 32 + 4 * kg;
  #pragma unroll
  for (int reg = 0; reg < 16; ++reg) {
    const int row = rb0 + (reg & 3) + 8 * (reg >> 2);
    Yo[(size_t)row * DD + col] = f2bf(fmaxf(acc[reg] + bvv, 0.f));
  }
}

// ---------------------------------------------------------------------------
// Epilogue: per (b,i) node. Neighbor indices precomputed (scalar loads).
// Gather at 16B/lane: threads 0-127 sum Ya chunks, 128-255 sum Yh; Yl as
// ushort4 by all 256. Head-major LDS; per-head softmax; head-mean.
// XCD-swizzled: batch b -> XCD b.   [byte-identical to R11]
// ---------------------------------------------------------------------------
__global__ __launch_bounds__(256)
void colight_epilogue(const int* __restrict__ idxbuf,
                      const unsigned short* __restrict__ Ylb,
                      const unsigned short* __restrict__ Yab,
                      const unsigned short* __restrict__ Yhb,
                      float* __restrict__ out) {
  const int bid = blockIdx.x;
  const int bi = (bid & 7) * NN + (bid >> 3);   // batch = bid&7 -> XCD bid&7

  __shared__ float sA[NH][LL];
  __shared__ float sH[NH][LL];
  __shared__ float sL[NH][LL];
  __shared__ float sPart[NH][LL];

  const int t = threadIdx.x;

  // neighbor row indices (include batch row-base): wave-uniform -> s_load
  const int* ib = idxbuf + bi * KNBR;
  int ridx[KNBR];
  #pragma unroll
  for (int k = 0; k < KNBR; ++k) ridx[k] = ib[k];

  // gather + sum 8 neighbor rows, 16B/lane (chunk c = 8 bf16 = latent l=c)
  {
    const int c = t & 127;
    const unsigned short* src = (t < 128) ? Yab : Yhb;
    float acc8[8] = {};
    #pragma unroll
    for (int k = 0; k < KNBR; ++k) {
      const uint4 v = *(const uint4*)&src[(size_t)ridx[k] * DD + c * 8];
      const unsigned* pw = (const unsigned*)&v;
      #pragma unroll
      for (int wq = 0; wq < 4; ++wq) {
        acc8[wq * 2 + 0] += __uint_as_float(pw[wq] << 16);
        acc8[wq * 2 + 1] += __uint_as_float(pw[wq] & 0xffff0000u);
      }
    }
    float (*dst)[LL] = (t < 128) ? sA : sH;
    #pragma unroll
    for (int e = 0; e < 8; ++e) dst[e][c] = acc8[e];   // h=e, l=c
  }
  // own Yl row: all 256 threads, 4 elems each (d0 = t*4 -> l = t>>1)
  {
    const int d0 = t * 4;
    ushort4 vl = *(const ushort4*)&Ylb[(size_t)bi * DD + d0];
    const int gl = t >> 1, h0 = (t & 1) * 4;
    sL[h0 + 0][gl] = bf2f(vl.x); sL[h0 + 1][gl] = bf2f(vl.y);
    sL[h0 + 2][gl] = bf2f(vl.z); sL[h0 + 3][gl] = bf2f(vl.w);
  }
  __syncthreads();

  // per-head softmax over L=128: head h = t>>5, lane j = t&31, 4 elems/lane
  const int h = t >> 5, j = t & 31;
  float z[4];
  float mx = -1e30f;
  #pragma unroll
  for (int q = 0; q < 4; ++q) {
    const int l = j + q * 32;
    z[q] = sL[h][l] * sA[h][l];
    mx = fmaxf(mx, z[q]);
  }
  #pragma unroll
  for (int m = 1; m <= 16; m <<= 1)
    mx = fmaxf(mx, __shfl_xor(mx, m, 32));

  float se = 0.f;
  #pragma unroll
  for (int q = 0; q < 4; ++q) {
    z[q] = __expf(z[q] - mx);
    se += z[q];
  }
  #pragma unroll
  for (int m = 1; m <= 16; m <<= 1)
    se += __shfl_xor(se, m, 32);
  const float inv = 1.f / se;

  #pragma unroll
  for (int q = 0; q < 4; ++q) {
    const int l = j + q * 32;
    sPart[h][l] = z[q] * inv * sH[h][l] * 0.125f;  // mean over 8 heads
  }
  __syncthreads();

  if (t < LL) {
    float o = 0.f;
    #pragma unroll
    for (int hh = 0; hh < NH; ++hh) o += sPart[hh][t];
    out[(size_t)bi * LL + t] = o;
  }
}

// ---------------------------------------------------------------------------
extern "C" void kernel_launch(void* const* d_in, const int* in_sizes, int n_in,
                              void* d_out, int out_size, void* d_ws, size_t ws_size,
                              hipStream_t stream) {
  const float* E   = (const float*)d_in[0];
  const float* adj = (const float*)d_in[1];
  const float* Wl  = (const float*)d_in[2];
  const float* bl  = (const float*)d_in[3];
  const float* Wa  = (const float*)d_in[4];
  const float* ba  = (const float*)d_in[5];
  const float* Wh  = (const float*)d_in[6];
  const float* bh  = (const float*)d_in[7];
  float* out = (float*)d_out;

  char* ws = (char*)d_ws;
  unsigned short* Ylb = (unsigned short*)ws;                       // 2 MB
  unsigned short* Yab = (unsigned short*)(ws + 2 * 1024 * 1024);   // 2 MB
  unsigned short* Yhb = (unsigned short*)(ws + 4 * 1024 * 1024);   // 2 MB
  unsigned short* Eb  = (unsigned short*)(ws + 6 * 1024 * 1024);   // 2 MB
  unsigned short* Wt  = (unsigned short*)(ws + 8 * 1024 * 1024);   // 6 MB
  int*            idxb = (int*)(ws + 14 * 1024 * 1024);            // 32 KB

  prep<<<dim3(16, 16, 4), dim3(256), 0, stream>>>(E, Wl, Wa, Wh, Eb, Wt);
  gemm3_mfma<<<dim3(1024), dim3(256), 0, stream>>>(Eb, Wt, bl, ba, bh,
                                                   adj, idxb, Ylb, Yab, Yhb);
  colight_epilogue<<<dim3(BB * NN), dim3(256), 0, stream>>>(idxb, Ylb, Yab, Yhb, out);
}

// Round 15
// 27.450 us; speedup vs baseline: 1.0663x; 1.0663x over previous
//
#include <hip/hip_runtime.h>
#include <math.h>

#define DD 1024   // total dim
#define NN 128    // nodes
#define BB 8      // batch
#define KNBR 8    // neighbors
#define NH 8      // heads
#define LL 128    // latent

typedef __attribute__((ext_vector_type(8))) short short8v;
typedef __attribute__((ext_vector_type(4))) float f32x4;

#define GLDS(gptr, lptr)                                                      \
  __builtin_amdgcn_global_load_lds(                                           \
      (const __attribute__((address_space(1))) void*)(gptr),                  \
      (__attribute__((address_space(3))) void*)(lptr), 16, 0, 0)

__device__ __forceinline__ unsigned short f2bf(float x) {
  unsigned u = __float_as_uint(x);
  unsigned r = u + 0x7fff + ((u >> 16) & 1);   // round-to-nearest-even
  return (unsigned short)(r >> 16);
}
__device__ __forceinline__ float bf2f(unsigned short u) {
  return __uint_as_float((unsigned)u << 16);
}

// ---------------------------------------------------------------------------
// Prep: z<3 -> convert+transpose W[z] (64x64 LDS tiles); z==3 -> convert E.
// grid (16,16,4), 256 threads.   [proven since R2]
// ---------------------------------------------------------------------------
__global__ __launch_bounds__(256)
void prep(const float* __restrict__ E,
          const float* __restrict__ Wl, const float* __restrict__ Wa,
          const float* __restrict__ Wh,
          unsigned short* __restrict__ Eb, unsigned short* __restrict__ Wt) {
  const int z = blockIdx.z;
  const int t = threadIdx.x;

  if (z == 3) {   // E convert: 256 blocks x 256 threads x 16 elems
    const int bid = blockIdx.y * 16 + blockIdx.x;
    const int i0 = bid * 4096 + t * 16;
    #pragma unroll
    for (int q = 0; q < 2; ++q) {
      const int i = i0 + q * 8;
      float4 a = *(const float4*)&E[i];
      float4 c = *(const float4*)&E[i + 4];
      union { unsigned short u[8]; uint4 v; } o;
      o.u[0] = f2bf(a.x); o.u[1] = f2bf(a.y); o.u[2] = f2bf(a.z); o.u[3] = f2bf(a.w);
      o.u[4] = f2bf(c.x); o.u[5] = f2bf(c.y); o.u[6] = f2bf(c.z); o.u[7] = f2bf(c.w);
      *(uint4*)&Eb[i] = o.v;
    }
    return;
  }

  const float* W = (z == 0) ? Wl : (z == 1) ? Wa : Wh;
  unsigned short* out = Wt + (size_t)z * DD * DD;

  __shared__ unsigned short tile[64][65];
  const int tx = t & 15, ty = t >> 4;
  const int r0 = blockIdx.y * 64, c0 = blockIdx.x * 64;

  #pragma unroll
  for (int i = 0; i < 4; ++i) {
    const int r = ty + i * 16;
    float4 v = *(const float4*)&W[(size_t)(r0 + r) * DD + c0 + tx * 4];
    tile[r][tx * 4 + 0] = f2bf(v.x);
    tile[r][tx * 4 + 1] = f2bf(v.y);
    tile[r][tx * 4 + 2] = f2bf(v.z);
    tile[r][tx * 4 + 3] = f2bf(v.w);
  }
  __syncthreads();
  #pragma unroll
  for (int i = 0; i < 4; ++i) {
    const int rr = ty + i * 16;   // output row = W column c0+rr
    ushort4 o;
    o.x = tile[tx * 4 + 0][rr];
    o.y = tile[tx * 4 + 1][rr];
    o.z = tile[tx * 4 + 2][rr];
    o.w = tile[tx * 4 + 3][rr];
    *(ushort4*)&out[(size_t)(c0 + rr) * DD + r0 + tx * 4] = o;
  }
}

// ---------------------------------------------------------------------------
// MFMA GEMM + hidden adj scan. Grid 1024 (1024%8==0), bijective XCD swizzle:
// per-XCD locals 0..95 = GEMM jobs (768 total, 3 blocks/CU); locals 96..127
// = adj-scan jobs (256, dispatched last -> hide under the gemm phase).
// GEMM: 64x64 tile, BK=64, 4 waves, wave tile 32x32, 8x 16x16x32 MFMA into
// 4 independent accumulators (max ILP), 3-buffer LDS counted-vmcnt pipeline,
// XOR-swizzle both-sides, setprio around the MFMA cluster.  [R11 proven]
// ---------------------------------------------------------------------------
__global__ __launch_bounds__(256)
void gemm3_mfma(const unsigned short* __restrict__ Eb,
                const unsigned short* __restrict__ Wt,
                const float* __restrict__ bl, const float* __restrict__ ba,
                const float* __restrict__ bh,
                const float* __restrict__ adj, int* __restrict__ idxbuf,
                unsigned short* __restrict__ Ylb,
                unsigned short* __restrict__ Yab,
                unsigned short* __restrict__ Yhb) {
  const int orig = blockIdx.x;
  const int xcd = orig & 7;
  const int local = orig >> 3;       // 0..127 per XCD

  const int t = threadIdx.x;

  if (local >= 96) {   // ---- adj one-hot scan: 4 nodes/block, 1 wave/node ----
    const int s = xcd * 32 + (local - 96);   // 0..255
    const int bi = s * 4 + (t >> 6);         // 0..1023
    const int lane = t & 63;
    const int k = lane >> 3;                 // neighbor row 0..7
    const int c0 = (lane & 7) * 16;          // this lane scans 16 cols
    const int rbase = (bi >> 7) * NN;
    const float* row = adj + ((size_t)bi * KNBR + k) * NN + c0;
    int found = -1;
    #pragma unroll
    for (int q = 0; q < 4; ++q) {
      float4 v = *(const float4*)&row[q * 4];
      const int base = c0 + q * 4;
      if (v.x > 0.5f) found = base;
      if (v.y > 0.5f) found = base + 1;
      if (v.z > 0.5f) found = base + 2;
      if (v.w > 0.5f) found = base + 3;
    }
    if (found >= 0) idxbuf[bi * KNBR + k] = rbase + found;
    return;
  }

  const int job = xcd * 96 + local;  // 0..767
  const int mat = job >> 8;          // /256
  const int rem = job & 255;
  const int bx = rem >> 4;           // col panel 0..15
  const int by = rem & 15;           // row panel 0..15

  const unsigned short* Bg = Wt + (size_t)mat * DD * DD;
  const float* bias = (mat == 0) ? bl : (mat == 1) ? ba : bh;

  __shared__ unsigned short As[3][64 * 64];
  __shared__ unsigned short Bs[3][64 * 64];

  const int lane = t & 63;
  const int w = t >> 6;            // wave 0..3
  const int wr = w >> 1, wc = w & 1;
  const int brow = by * 64, bcol = bx * 64;

  // staging: thread t -> tile row (t>>3) [+32 for 2nd issue], chunk (t&7).
  // swizzle: LDS row r, linear chunk q holds global chunk q ^ (r&7).
  const int srow = t >> 3;                      // 0..31
  const int sk = (((t & 7) ^ (srow & 7)) * 8);  // source k-offset (elems)
  const unsigned short* gA = Eb + (size_t)(brow + srow) * DD + sk;
  const unsigned short* gB = Bg + (size_t)(bcol + srow) * DD + sk;
  const int ldsoff = w * 512;   // elems; wave-uniform base (+ lane*16B by HW)

  const int lrow = lane & 15, lg = lane >> 4;

  // swizzled fragment indices: row r, logical chunk (kk*4+lg) -> chunk^(r&7)
  int aidx[2][2], bidx[2][2];
  #pragma unroll
  for (int kk = 0; kk < 2; ++kk)
    #pragma unroll
    for (int m = 0; m < 2; ++m) {
      const int ra = wr * 32 + m * 16 + lrow;
      aidx[kk][m] = ra * 64 + (((kk * 4 + lg) ^ (ra & 7)) * 8);
      const int rb = wc * 32 + m * 16 + lrow;
      bidx[kk][m] = rb * 64 + (((kk * 4 + lg) ^ (rb & 7)) * 8);
    }

  // preload bias and force completion so loop vmcnt counting stays exact
  float bv0 = bias[bcol + wc * 32 + lrow];
  float bv1 = bias[bcol + wc * 32 + 16 + lrow];
  asm volatile("" : "+v"(bv0), "+v"(bv1));   // materialize (drains their loads)

  f32x4 acc[2][2] = {};

#define STAGE(q, kt) do {                                                     \
    const int k0_ = (kt) * 64;                                                \
    GLDS(gA + k0_,           &As[q][ldsoff]);                                 \
    GLDS(gA + k0_ + 32 * DD, &As[q][2048 + ldsoff]);                          \
    GLDS(gB + k0_,           &Bs[q][ldsoff]);                                 \
    GLDS(gB + k0_ + 32 * DD, &Bs[q][2048 + ldsoff]);                          \
  } while (0)

  STAGE(0, 0);   // 4 vm ops in flight
  STAGE(1, 1);   // 8 in flight

  #pragma unroll
  for (int kt = 0; kt < 16; ++kt) {
    const int p = kt % 3;
    // wait for tile kt's 4 loads (oldest); tile kt+1's 4 stay in flight
    if (kt != 15) asm volatile("s_waitcnt vmcnt(4)" ::: "memory");
    else          asm volatile("s_waitcnt vmcnt(0)" ::: "memory");
    __builtin_amdgcn_s_barrier();   // all waves' slices of buf p landed;
                                    // also: all reads of buf (p+2)%3 done
    if (kt + 2 < 16) STAGE((kt + 2) % 3, kt + 2);   // overwrite tile kt-1's buf

    short8v a[2][2], b[2][2];
    #pragma unroll
    for (int kk = 0; kk < 2; ++kk)
      #pragma unroll
      for (int m = 0; m < 2; ++m) {
        a[kk][m] = *(const short8v*)&As[p][aidx[kk][m]];
        b[kk][m] = *(const short8v*)&Bs[p][bidx[kk][m]];
      }

    __builtin_amdgcn_s_setprio(1);
    #pragma unroll
    for (int kk = 0; kk < 2; ++kk)
      #pragma unroll
      for (int m = 0; m < 2; ++m)
        #pragma unroll
        for (int n = 0; n < 2; ++n)
          acc[m][n] = __builtin_amdgcn_mfma_f32_16x16x32_bf16(
              a[kk][m], b[kk][n], acc[m][n], 0, 0, 0);
    __builtin_amdgcn_s_setprio(0);
  }
#undef STAGE

  // epilogue: bias + relu, bf16 store (C/D: col = lane&15, row = (lane>>4)*4+j)
  unsigned short* Yo = (mat == 0) ? Ylb : (mat == 1) ? Yab : Yhb;
  #pragma unroll
  for (int m = 0; m < 2; ++m) {
    #pragma unroll
    for (int n = 0; n < 2; ++n) {
      const int col = bcol + wc * 32 + n * 16 + lrow;
      const int r0  = brow + wr * 32 + m * 16 + lg * 4;
      const float bv = n ? bv1 : bv0;
      #pragma unroll
      for (int j = 0; j < 4; ++j)
        Yo[(size_t)(r0 + j) * DD + col] = f2bf(fmaxf(acc[m][n][j] + bv, 0.f));
    }
  }
}

// ---------------------------------------------------------------------------
// Epilogue: per (b,i) node. Neighbor indices precomputed (scalar loads).
// Gather at 16B/lane: threads 0-127 sum Ya chunks (uint4 = 8 bf16),
// threads 128-255 sum Yh; Yl as ushort4 by all 256. Head-major LDS
// (element d: l = d>>3, h = d&7 -> s[h][l]); per-head softmax; head-mean.
// XCD-swizzled: batch b -> XCD b.   [R11 proven]
// ---------------------------------------------------------------------------
__global__ __launch_bounds__(256)
void colight_epilogue(const int* __restrict__ idxbuf,
                      const unsigned short* __restrict__ Ylb,
                      const unsigned short* __restrict__ Yab,
                      const unsigned short* __restrict__ Yhb,
                      float* __restrict__ out) {
  const int bid = blockIdx.x;
  const int bi = (bid & 7) * NN + (bid >> 3);   // batch = bid&7 -> XCD bid&7

  __shared__ float sA[NH][LL];
  __shared__ float sH[NH][LL];
  __shared__ float sL[NH][LL];
  __shared__ float sPart[NH][LL];

  const int t = threadIdx.x;

  // neighbor row indices (include batch row-base): wave-uniform -> s_load
  const int* ib = idxbuf + bi * KNBR;
  int ridx[KNBR];
  #pragma unroll
  for (int k = 0; k < KNBR; ++k) ridx[k] = ib[k];

  // gather + sum 8 neighbor rows, 16B/lane (chunk c = 8 bf16 = latent l=c)
  {
    const int c = t & 127;
    const unsigned short* src = (t < 128) ? Yab : Yhb;
    float acc8[8] = {};
    #pragma unroll
    for (int k = 0; k < KNBR; ++k) {
      const uint4 v = *(const uint4*)&src[(size_t)ridx[k] * DD + c * 8];
      const unsigned* pw = (const unsigned*)&v;
      #pragma unroll
      for (int wq = 0; wq < 4; ++wq) {
        acc8[wq * 2 + 0] += __uint_as_float(pw[wq] << 16);
        acc8[wq * 2 + 1] += __uint_as_float(pw[wq] & 0xffff0000u);
      }
    }
    float (*dst)[LL] = (t < 128) ? sA : sH;
    #pragma unroll
    for (int e = 0; e < 8; ++e) dst[e][c] = acc8[e];   // h=e, l=c
  }
  // own Yl row: all 256 threads, 4 elems each (d0 = t*4 -> l = t>>1)
  {
    const int d0 = t * 4;
    ushort4 vl = *(const ushort4*)&Ylb[(size_t)bi * DD + d0];
    const int gl = t >> 1, h0 = (t & 1) * 4;
    sL[h0 + 0][gl] = bf2f(vl.x); sL[h0 + 1][gl] = bf2f(vl.y);
    sL[h0 + 2][gl] = bf2f(vl.z); sL[h0 + 3][gl] = bf2f(vl.w);
  }
  __syncthreads();

  // per-head softmax over L=128: head h = t>>5, lane j = t&31, 4 elems/lane
  const int h = t >> 5, j = t & 31;
  float z[4];
  float mx = -1e30f;
  #pragma unroll
  for (int q = 0; q < 4; ++q) {
    const int l = j + q * 32;
    z[q] = sL[h][l] * sA[h][l];
    mx = fmaxf(mx, z[q]);
  }
  #pragma unroll
  for (int m = 1; m <= 16; m <<= 1)
    mx = fmaxf(mx, __shfl_xor(mx, m, 32));

  float se = 0.f;
  #pragma unroll
  for (int q = 0; q < 4; ++q) {
    z[q] = __expf(z[q] - mx);
    se += z[q];
  }
  #pragma unroll
  for (int m = 1; m <= 16; m <<= 1)
    se += __shfl_xor(se, m, 32);
  const float inv = 1.f / se;

  #pragma unroll
  for (int q = 0; q < 4; ++q) {
    const int l = j + q * 32;
    sPart[h][l] = z[q] * inv * sH[h][l] * 0.125f;  // mean over 8 heads
  }
  __syncthreads();

  if (t < LL) {
    float o = 0.f;
    #pragma unroll
    for (int hh = 0; hh < NH; ++hh) o += sPart[hh][t];
    out[(size_t)bi * LL + t] = o;
  }
}

// ---------------------------------------------------------------------------
extern "C" void kernel_launch(void* const* d_in, const int* in_sizes, int n_in,
                              void* d_out, int out_size, void* d_ws, size_t ws_size,
                              hipStream_t stream) {
  const float* E   = (const float*)d_in[0];
  const float* adj = (const float*)d_in[1];
  const float* Wl  = (const float*)d_in[2];
  const float* bl  = (const float*)d_in[3];
  const float* Wa  = (const float*)d_in[4];
  const float* ba  = (const float*)d_in[5];
  const float* Wh  = (const float*)d_in[6];
  const float* bh  = (const float*)d_in[7];
  float* out = (float*)d_out;

  char* ws = (char*)d_ws;
  unsigned short* Ylb = (unsigned short*)ws;                       // 2 MB
  unsigned short* Yab = (unsigned short*)(ws + 2 * 1024 * 1024);   // 2 MB
  unsigned short* Yhb = (unsigned short*)(ws + 4 * 1024 * 1024);   // 2 MB
  unsigned short* Eb  = (unsigned short*)(ws + 6 * 1024 * 1024);   // 2 MB
  unsigned short* Wt  = (unsigned short*)(ws + 8 * 1024 * 1024);   // 6 MB
  int*            idxb = (int*)(ws + 14 * 1024 * 1024);            // 32 KB

  prep<<<dim3(16, 16, 4), dim3(256), 0, stream>>>(E, Wl, Wa, Wh, Eb, Wt);
  gemm3_mfma<<<dim3(1024), dim3(256), 0, stream>>>(Eb, Wt, bl, ba, bh,
                                                   adj, idxb, Ylb, Yab, Yhb);
  colight_epilogue<<<dim3(BB * NN), dim3(256), 0, stream>>>(idxb, Ylb, Yab, Yhb, out);
}